// Round 1
// baseline (7708.259 us; speedup 1.0000x reference)
//
#include <hip/hip_runtime.h>

// ---------------- problem constants ----------------
#define NN 100000     // nodes
#define NE 800000     // edges
#define DIN 256
#define DHID 256
#define DOUT 128
#define DEP 256
#define NCLS 40

static constexpr size_t OFF_EF = (size_t)NN * DOUT;                 // edge_feats
static constexpr size_t OFF_LG = OFF_EF + (size_t)NE * DOUT;        // logits
static constexpr size_t OFF_EI = OFF_LG + (size_t)NN * NCLS;        // edge_index (as float)

// ---------------- utility kernels ----------------

// Detect int64 vs int32 edge_index layout and convert to int32 buffer.
__global__ __launch_bounds__(256) void convert_ei_kernel(const int* __restrict__ ei32,
                                                         int* __restrict__ eidx, int n2e) {
    __shared__ int is64;
    if (threadIdx.x == 0) {
        int ored = 0;
        for (int i = 0; i < 64; ++i) ored |= ei32[2 * i + 1];
        is64 = (ored == 0) ? 1 : 0;   // int64 little-endian: high words all zero
    }
    __syncthreads();
    int i = blockIdx.x * 256 + threadIdx.x;
    if (i < n2e) {
        if (is64) {
            const long long* e64 = (const long long*)ei32;
            eidx[i] = (int)e64[i];
        } else {
            eidx[i] = ei32[i];
        }
    }
}

__global__ __launch_bounds__(256) void zero_kernel(float4* __restrict__ p, int n4) {
    int i = blockIdx.x * 256 + threadIdx.x;
    if (i < n4) p[i] = make_float4(0.f, 0.f, 0.f, 0.f);
}

__global__ __launch_bounds__(256) void degree_kernel(const int* __restrict__ eidx,
                                                     float* __restrict__ deg) {
    int e = blockIdx.x * 256 + threadIdx.x;
    if (e < NE) atomicAdd(&deg[eidx[NE + e]], 1.0f);
}

__global__ __launch_bounds__(256) void dinv_kernel(const float* __restrict__ deg,
                                                   float* __restrict__ dinv) {
    int v = blockIdx.x * 256 + threadIdx.x;
    if (v < NN) dinv[v] = rsqrtf(deg[v] + 1.0f);   // +1 self-loop; deg>=1 always
}

__global__ __launch_bounds__(256) void copyei_kernel(const int* __restrict__ eidx,
                                                     float* __restrict__ out, int n2e) {
    int i = blockIdx.x * 256 + threadIdx.x;
    if (i < n2e) out[i] = (float)eidx[i];
}

// ---------------- generic 32-row GEMM: C[M,N] = A[M,K] @ B[K,N] (+bias) ----------------
// 256 threads, TM=32 rows/block. K,N <= 256. JPT cols per thread.
template <int K, int N, int JPT, bool BIAS, int PAD>
__global__ __launch_bounds__(256) void gemm32_kernel(const float* __restrict__ A,
                                                     const float* __restrict__ B,
                                                     const float* __restrict__ bias,
                                                     float* __restrict__ C) {
    constexpr int TPR = N / JPT;       // threads covering one row's N cols
    constexpr int GROUPS = 256 / TPR;  // row groups
    constexpr int RPT = 32 / GROUPS;   // rows per thread
    __shared__ float As[32][K + PAD];

    const int t = threadIdx.x;
    const size_t m0 = (size_t)blockIdx.x * 32;

    // stage A tile (M is an exact multiple of 32 for all uses)
    for (int idx4 = t; idx4 < 32 * K / 4; idx4 += 256) {
        int idx = idx4 * 4;
        int r = idx / K, cc = idx % K;
        float4 v = *reinterpret_cast<const float4*>(A + (m0 + r) * K + cc);
        As[r][cc + 0] = v.x; As[r][cc + 1] = v.y;
        As[r][cc + 2] = v.z; As[r][cc + 3] = v.w;
    }
    __syncthreads();

    const int g = t / TPR;
    const int jbase = (t % TPR) * JPT;

    float acc[RPT][JPT];
#pragma unroll
    for (int i = 0; i < RPT; ++i)
#pragma unroll
        for (int j = 0; j < JPT; ++j) acc[i][j] = 0.f;

    if constexpr ((JPT % 4) == 0 && PAD == 0) {
        for (int k0 = 0; k0 < K; k0 += 4) {
            float4 a4[RPT];
#pragma unroll
            for (int i = 0; i < RPT; ++i)
                a4[i] = *reinterpret_cast<const float4*>(&As[g * RPT + i][k0]);
#pragma unroll
            for (int kk = 0; kk < 4; ++kk) {
                float b[JPT];
#pragma unroll
                for (int j4 = 0; j4 < JPT / 4; ++j4) {
                    float4 bv = *reinterpret_cast<const float4*>(B + (size_t)(k0 + kk) * N + jbase + j4 * 4);
                    b[j4 * 4 + 0] = bv.x; b[j4 * 4 + 1] = bv.y;
                    b[j4 * 4 + 2] = bv.z; b[j4 * 4 + 3] = bv.w;
                }
#pragma unroll
                for (int i = 0; i < RPT; ++i) {
                    float a = (kk == 0) ? a4[i].x : (kk == 1) ? a4[i].y : (kk == 2) ? a4[i].z : a4[i].w;
#pragma unroll
                    for (int j = 0; j < JPT; ++j) acc[i][j] = fmaf(a, b[j], acc[i][j]);
                }
            }
        }
    } else {
        for (int k = 0; k < K; ++k) {
            float b[JPT];
#pragma unroll
            for (int j = 0; j < JPT; ++j) b[j] = B[(size_t)k * N + jbase + j];
#pragma unroll
            for (int i = 0; i < RPT; ++i) {
                float a = As[g * RPT + i][k];
#pragma unroll
                for (int j = 0; j < JPT; ++j) acc[i][j] = fmaf(a, b[j], acc[i][j]);
            }
        }
    }

#pragma unroll
    for (int i = 0; i < RPT; ++i) {
        size_t m = m0 + g * RPT + i;
#pragma unroll
        for (int j = 0; j < JPT; ++j) {
            float v = acc[i][j];
            if constexpr (BIAS) v += bias[jbase + j];
            C[m * N + jbase + j] = v;
        }
    }
}

// ---------------- edge scatter (atomic) ----------------
// D=256: 64 lanes/edge (float4 each). D=128: 32 lanes/edge.
__global__ __launch_bounds__(256) void scatter256_kernel(const float* __restrict__ src,
                                                         const int* __restrict__ eidx,
                                                         const float* __restrict__ dinv,
                                                         float* __restrict__ agg) {
    int gid = blockIdx.x * 256 + threadIdx.x;
    int e = gid >> 6, l = gid & 63;
    int r = eidx[e], c = eidx[NE + e];
    float nrm = dinv[r] * dinv[c];
    float4 v = reinterpret_cast<const float4*>(src + (size_t)r * 256)[l];
    float* dst = agg + (size_t)c * 256 + l * 4;
    atomicAdd(dst + 0, nrm * v.x);
    atomicAdd(dst + 1, nrm * v.y);
    atomicAdd(dst + 2, nrm * v.z);
    atomicAdd(dst + 3, nrm * v.w);
}

__global__ __launch_bounds__(256) void scatter128_kernel(const float* __restrict__ src,
                                                         const int* __restrict__ eidx,
                                                         const float* __restrict__ dinv,
                                                         float* __restrict__ agg) {
    int gid = blockIdx.x * 256 + threadIdx.x;
    int e = gid >> 5, l = gid & 31;
    int r = eidx[e], c = eidx[NE + e];
    float nrm = dinv[r] * dinv[c];
    float4 v = reinterpret_cast<const float4*>(src + (size_t)r * 128)[l];
    float* dst = agg + (size_t)c * 128 + l * 4;
    atomicAdd(dst + 0, nrm * v.x);
    atomicAdd(dst + 1, nrm * v.y);
    atomicAdd(dst + 2, nrm * v.z);
    atomicAdd(dst + 3, nrm * v.w);
}

// ---------------- self-loop + bias (+relu) epilogues ----------------
__global__ __launch_bounds__(256) void finish1_kernel(float* __restrict__ agg1,   // becomes h
                                                      const float* __restrict__ xw,
                                                      const float* __restrict__ dinv,
                                                      const float* __restrict__ b1) {
    int gid = blockIdx.x * 256 + threadIdx.x;
    int v = gid >> 6, l = gid & 63;
    float di = dinv[v];
    float s = di * di;
    float4 a = reinterpret_cast<float4*>(agg1 + (size_t)v * 256)[l];
    float4 xv = reinterpret_cast<const float4*>(xw + (size_t)v * 256)[l];
    float4 bb = reinterpret_cast<const float4*>(b1)[l];
    a.x = fmaxf(fmaf(s, xv.x, a.x) + bb.x, 0.f);
    a.y = fmaxf(fmaf(s, xv.y, a.y) + bb.y, 0.f);
    a.z = fmaxf(fmaf(s, xv.z, a.z) + bb.z, 0.f);
    a.w = fmaxf(fmaf(s, xv.w, a.w) + bb.w, 0.f);
    reinterpret_cast<float4*>(agg1 + (size_t)v * 256)[l] = a;
}

__global__ __launch_bounds__(256) void finish2_kernel(const float* __restrict__ agg2,
                                                      const float* __restrict__ hw,
                                                      const float* __restrict__ dinv,
                                                      const float* __restrict__ b2,
                                                      float* __restrict__ f) {
    int gid = blockIdx.x * 256 + threadIdx.x;
    int v = gid >> 5, l = gid & 31;
    float di = dinv[v];
    float s = di * di;
    float4 a = reinterpret_cast<const float4*>(agg2 + (size_t)v * 128)[l];
    float4 xv = reinterpret_cast<const float4*>(hw + (size_t)v * 128)[l];
    float4 bb = reinterpret_cast<const float4*>(b2)[l];
    a.x = fmaf(s, xv.x, a.x) + bb.x;
    a.y = fmaf(s, xv.y, a.y) + bb.y;
    a.z = fmaf(s, xv.z, a.z) + bb.z;
    a.w = fmaf(s, xv.w, a.w) + bb.w;
    reinterpret_cast<float4*>(f + (size_t)v * 128)[l] = a;
}

// ---------------- fused edge MLP ----------------
// Per block: 32 edges. ef = concat(f[r],f[c]) -> LDS; hid = relu(ef@Wp1+bp1) -> LDS;
// out = hid@Wp2+bp2 -> global. 256 threads, 64 KiB LDS.
__global__ __launch_bounds__(256) void edgemlp_kernel(const float* __restrict__ f,
                                                      const int* __restrict__ eidx,
                                                      const float* __restrict__ Wp1,
                                                      const float* __restrict__ bp1,
                                                      const float* __restrict__ Wp2,
                                                      const float* __restrict__ bp2,
                                                      float* __restrict__ out) {
    __shared__ float ef[32][256];
    __shared__ float hid[32][256];
    const int t = threadIdx.x;
    const int e0 = blockIdx.x * 32;

    {   // gather: 8 threads per edge, each 8 float4
        int le = t >> 3, sub = t & 7;
        int e = e0 + le;
        int r = eidx[e], c = eidx[NE + e];
        const float* src = (sub < 4) ? (f + (size_t)r * 128 + sub * 32)
                                     : (f + (size_t)c * 128 + (sub - 4) * 32);
#pragma unroll
        for (int i = 0; i < 8; ++i) {
            float4 v = reinterpret_cast<const float4*>(src)[i];
            float* dst = &ef[le][sub * 32 + i * 4];
            dst[0] = v.x; dst[1] = v.y; dst[2] = v.z; dst[3] = v.w;
        }
    }
    __syncthreads();

    const int g = t >> 5;           // 8 row groups x 4 rows
    {   // GEMM1: K=256, N=256, JPT=8
        const int jbase = (t & 31) * 8;
        float bias1[8];
#pragma unroll
        for (int j = 0; j < 8; ++j) bias1[j] = bp1[jbase + j];
        float acc[4][8];
#pragma unroll
        for (int i = 0; i < 4; ++i)
#pragma unroll
            for (int j = 0; j < 8; ++j) acc[i][j] = 0.f;
        for (int k0 = 0; k0 < 256; k0 += 4) {
            float4 a4[4];
#pragma unroll
            for (int i = 0; i < 4; ++i)
                a4[i] = *reinterpret_cast<const float4*>(&ef[g * 4 + i][k0]);
#pragma unroll
            for (int kk = 0; kk < 4; ++kk) {
                float4 b0 = *reinterpret_cast<const float4*>(Wp1 + (size_t)(k0 + kk) * 256 + jbase);
                float4 b1v = *reinterpret_cast<const float4*>(Wp1 + (size_t)(k0 + kk) * 256 + jbase + 4);
                float b[8] = {b0.x, b0.y, b0.z, b0.w, b1v.x, b1v.y, b1v.z, b1v.w};
#pragma unroll
                for (int i = 0; i < 4; ++i) {
                    float a = (kk == 0) ? a4[i].x : (kk == 1) ? a4[i].y : (kk == 2) ? a4[i].z : a4[i].w;
#pragma unroll
                    for (int j = 0; j < 8; ++j) acc[i][j] = fmaf(a, b[j], acc[i][j]);
                }
            }
        }
#pragma unroll
        for (int i = 0; i < 4; ++i)
#pragma unroll
            for (int j = 0; j < 8; ++j)
                hid[g * 4 + i][jbase + j] = fmaxf(acc[i][j] + bias1[j], 0.f);
    }
    __syncthreads();

    {   // GEMM2: K=256, N=128, JPT=4
        const int jbase = (t & 31) * 4;
        float bias2[4];
#pragma unroll
        for (int j = 0; j < 4; ++j) bias2[j] = bp2[jbase + j];
        float acc[4][4];
#pragma unroll
        for (int i = 0; i < 4; ++i)
#pragma unroll
            for (int j = 0; j < 4; ++j) acc[i][j] = 0.f;
        for (int k0 = 0; k0 < 256; k0 += 4) {
            float4 a4[4];
#pragma unroll
            for (int i = 0; i < 4; ++i)
                a4[i] = *reinterpret_cast<const float4*>(&hid[g * 4 + i][k0]);
#pragma unroll
            for (int kk = 0; kk < 4; ++kk) {
                float4 bv = *reinterpret_cast<const float4*>(Wp2 + (size_t)(k0 + kk) * 128 + jbase);
                float b[4] = {bv.x, bv.y, bv.z, bv.w};
#pragma unroll
                for (int i = 0; i < 4; ++i) {
                    float a = (kk == 0) ? a4[i].x : (kk == 1) ? a4[i].y : (kk == 2) ? a4[i].z : a4[i].w;
#pragma unroll
                    for (int j = 0; j < 4; ++j) acc[i][j] = fmaf(a, b[j], acc[i][j]);
                }
            }
        }
#pragma unroll
        for (int i = 0; i < 4; ++i) {
            float4 o;
            o.x = acc[i][0] + bias2[0];
            o.y = acc[i][1] + bias2[1];
            o.z = acc[i][2] + bias2[2];
            o.w = acc[i][3] + bias2[3];
            *reinterpret_cast<float4*>(out + (size_t)(e0 + g * 4 + i) * 128 + jbase) = o;
        }
    }
}

// ---------------- launch ----------------
extern "C" void kernel_launch(void* const* d_in, const int* in_sizes, int n_in,
                              void* d_out, int out_size, void* d_ws, size_t ws_size,
                              hipStream_t stream) {
    const float* x   = (const float*)d_in[0];
    const int*   ei  = (const int*)d_in[1];
    const float* W1  = (const float*)d_in[2];
    const float* b1  = (const float*)d_in[3];
    const float* W2  = (const float*)d_in[4];
    const float* b2  = (const float*)d_in[5];
    const float* Wp1 = (const float*)d_in[6];
    const float* bp1 = (const float*)d_in[7];
    const float* Wp2 = (const float*)d_in[8];
    const float* bp2 = (const float*)d_in[9];
    const float* Wc  = (const float*)d_in[10];
    const float* bc  = (const float*)d_in[11];
    float* out = (float*)d_out;
    float* ws  = (float*)d_ws;

    // ws layout (floats): deg[N] | agg1[N*256] | agg2[N*128] | dinv[N] | xw/hw[N*256] | eidx[2E] (int)
    float* deg  = ws;
    float* agg1 = ws + (size_t)NN;                 // later: h (in place)
    float* agg2 = agg1 + (size_t)NN * 256;
    float* dinv = agg2 + (size_t)NN * 128;
    float* xw   = dinv + (size_t)NN;               // later: hw (in place region)
    int*   eidx = (int*)(xw + (size_t)NN * 256);

    const int n2e = 2 * NE;

    // 1. normalize edge_index dtype into int32 buffer
    convert_ei_kernel<<<(n2e + 255) / 256, 256, 0, stream>>>(ei, eidx, n2e);
    // 2. zero deg + agg1 + agg2  (385*NN floats, exact multiple of 4)
    {
        int n4 = 385 * NN / 4;
        zero_kernel<<<(n4 + 255) / 256, 256, 0, stream>>>((float4*)ws, n4);
    }
    // 3. degree + dinv
    degree_kernel<<<NE / 256, 256, 0, stream>>>(eidx, deg);
    dinv_kernel<<<(NN + 255) / 256, 256, 0, stream>>>(deg, dinv);
    // 4. xw = x @ W1
    gemm32_kernel<256, 256, 8, false, 0><<<NN / 32, 256, 0, stream>>>(x, W1, nullptr, xw);
    // 5. agg1 += norm * xw[r]  (scatter to targets)
    scatter256_kernel<<<NE * 64 / 256, 256, 0, stream>>>(xw, eidx, dinv, agg1);
    // 6. h = relu(agg1 + dinv^2*xw + b1)   (in place in agg1)
    finish1_kernel<<<NN * 64 / 256, 256, 0, stream>>>(agg1, xw, dinv, b1);
    // 7. hw = h @ W2   (into xw region)
    gemm32_kernel<256, 128, 4, false, 0><<<NN / 32, 256, 0, stream>>>(agg1, W2, nullptr, xw);
    // 8. agg2 += norm * hw[r]
    scatter128_kernel<<<NE * 32 / 256, 256, 0, stream>>>(xw, eidx, dinv, agg2);
    // 9. f = agg2 + dinv^2*hw + b2  -> d_out chunk 0
    finish2_kernel<<<NN * 32 / 256, 256, 0, stream>>>(agg2, xw, dinv, b2, out);
    // 10. edge MLP -> d_out chunk 1
    edgemlp_kernel<<<NE / 32, 256, 0, stream>>>(out, eidx, Wp1, bp1, Wp2, bp2, out + OFF_EF);
    // 11. logits = f @ Wc + bc -> d_out chunk 2
    gemm32_kernel<128, 40, 5, true, 1><<<NN / 32, 256, 0, stream>>>(out, Wc, bc, out + OFF_LG);
    // 12. edge_index echo as float -> d_out chunk 3
    copyei_kernel<<<n2e / 256, 256, 0, stream>>>(eidx, out + OFF_EI, n2e);
}